// Round 6
// baseline (94.809 us; speedup 1.0000x reference)
//
#include <hip/hip_runtime.h>

#define N_   32
#define C_   3
#define T_   300
#define V_   25
#define OUT_ 96
#define ROWP 28              // padded row (float4-aligned)
#define ATS  (V_*ROWP)       // 700 floats per t-slice
#define TTP  5               // t's per k_powsum block
#define NCH  (T_/TTP)        // 60 chunks per n
#define TT2  10              // t's per k_out block
#define SEL  (3*V_*V_)       // 1875 floats per (n or partial) sum record

// ---------------------------------------------------------------------------
// K1: block = (n, 5-t chunk), 128 threads, LDS = A + A2 only (29.7 KB ->
// 5 blocks/CU). Symmetric 5x5-tile matmuls (15 upper tiles), A3 in registers
// reusing A's LDS after its t-sum flush. Partial sums, no atomics.
// ---------------------------------------------------------------------------
__global__ __launch_bounds__(128) void k_powsum(const float* __restrict__ xx,
                                                float* __restrict__ partial) {
    const int n = blockIdx.x, chunk = blockIdx.y;
    const int tid = threadIdx.x;

    __shared__ __align__(16) float xs[C_*TTP*ROWP];  // 420
    __shared__ __align__(16) float A [TTP*ATS];      // 3500
    __shared__ __align__(16) float A2[TTP*ATS];      // 3500

    const float* xxn = xx + (size_t)n * C_*T_*V_;
    const int t0 = chunk * TTP;

    // stage xs; pad cols: c==0 gets 1e18 so exp(-(1e18)^2) == 0 -> A pads = 0
    for (int i = tid; i < C_*TTP*ROWP; i += 128) {
        const int c = i/(TTP*ROWP), r = i%(TTP*ROWP), t = r/ROWP, u = r%ROWP;
        xs[i] = (u < V_) ? xxn[c*(T_*V_) + (t0+t)*V_ + u] : ((c==0)?1e18f:0.f);
    }
    // zero A2 pad columns (A2 tiles only write cols 0..24)
    if (tid < TTP*V_) {
        float* p = &A2[(tid/V_)*ATS + (tid%V_)*ROWP];
        p[25]=0.f; p[26]=0.f; p[27]=0.f;
    }
    __syncthreads();

    // build A: one (slot, v-row) per thread, vectorized over u (pads -> 0)
    if (tid < TTP*V_) {
        const int slot = tid/V_, v = tid%V_;
        const float* x0 = &xs[0*(TTP*ROWP) + slot*ROWP];
        const float* x1 = &xs[1*(TTP*ROWP) + slot*ROWP];
        const float* x2 = &xs[2*(TTP*ROWP) + slot*ROWP];
        const float xv0 = x0[v], xv1 = x1[v], xv2 = x2[v];
        float* Arow = &A[slot*ATS + v*ROWP];
        #pragma unroll
        for (int u4 = 0; u4 < ROWP; u4 += 4) {
            const float4 q0 = *(const float4*)&x0[u4];
            const float4 q1 = *(const float4*)&x1[u4];
            const float4 q2 = *(const float4*)&x2[u4];
            float4 a;
            {   float d0=xv0-q0.x, d1=xv1-q1.x, d2=xv2-q2.x;
                a.x = __expf(-(d0*d0 + d1*d1 + d2*d2)); }
            {   float d0=xv0-q0.y, d1=xv1-q1.y, d2=xv2-q2.y;
                a.y = __expf(-(d0*d0 + d1*d1 + d2*d2)); }
            {   float d0=xv0-q0.z, d1=xv1-q1.z, d2=xv2-q2.z;
                a.z = __expf(-(d0*d0 + d1*d1 + d2*d2)); }
            {   float d0=xv0-q0.w, d1=xv1-q1.w, d2=xv2-q2.w;
                a.w = __expf(-(d0*d0 + d1*d1 + d2*d2)); }
            *(float4*)&Arow[u4] = a;
        }
    }
    __syncthreads();

    // symmetric tile assignment: 15 upper tiles (i<=j) x 5 slots = 75 threads
    const bool act = (tid < TTP*15);
    const int slot = tid / 15;
    int ti = 0, tj = 0;
    {
        int r = tid % 15;
        #pragma unroll
        for (int i = 0; i < 5; ++i) {
            const int cnt = 5 - i;
            if (r < cnt) { ti = i; tj = i + r; break; }
            r -= cnt;
        }
    }
    const int vt = ti*5, ut = tj*5;

    // A2 tile = dot(A_row_v, A_row_u) (A symmetric, pads 0); mirror-write
    if (act) {
        float acc[5][5];
        #pragma unroll
        for (int a=0;a<5;a++)
            #pragma unroll
            for (int b2=0;b2<5;b2++) acc[a][b2]=0.f;
        const float* Ab = &A[slot*ATS];
        #pragma unroll
        for (int w = 0; w < ROWP; w += 4) {
            float4 ar[5], au[5];
            #pragma unroll
            for (int a=0;a<5;a++) ar[a] = *(const float4*)&Ab[(vt+a)*ROWP + w];
            #pragma unroll
            for (int b2=0;b2<5;b2++) au[b2] = *(const float4*)&Ab[(ut+b2)*ROWP + w];
            #pragma unroll
            for (int a=0;a<5;a++)
                #pragma unroll
                for (int b2=0;b2<5;b2++)
                    acc[a][b2] += ar[a].x*au[b2].x + ar[a].y*au[b2].y
                                + ar[a].z*au[b2].z + ar[a].w*au[b2].w;
        }
        float* A2b = &A2[slot*ATS];
        #pragma unroll
        for (int a=0;a<5;a++)
            #pragma unroll
            for (int b2=0;b2<5;b2++) {
                A2b[(vt+a)*ROWP + ut+b2] = acc[a][b2];
                A2b[(ut+b2)*ROWP + vt+a] = acc[a][b2];
            }
    }
    __syncthreads();

    // A3 tile in REGISTERS = dot(A2_row_v, A_row_u); A2 pads are 0
    float acc3[5][5];
    if (act) {
        #pragma unroll
        for (int a=0;a<5;a++)
            #pragma unroll
            for (int b2=0;b2<5;b2++) acc3[a][b2]=0.f;
        const float* Ab  = &A[slot*ATS];
        const float* A2b = &A2[slot*ATS];
        #pragma unroll
        for (int w = 0; w < ROWP; w += 4) {
            float4 ar[5], au[5];
            #pragma unroll
            for (int a=0;a<5;a++) ar[a] = *(const float4*)&A2b[(vt+a)*ROWP + w];
            #pragma unroll
            for (int b2=0;b2<5;b2++) au[b2] = *(const float4*)&Ab[(ut+b2)*ROWP + w];
            #pragma unroll
            for (int a=0;a<5;a++)
                #pragma unroll
                for (int b2=0;b2<5;b2++)
                    acc3[a][b2] += ar[a].x*au[b2].x + ar[a].y*au[b2].y
                                 + ar[a].z*au[b2].z + ar[a].w*au[b2].w;
        }
    }

    // t-sum A and A2 straight from LDS -> partial (read-only, no barrier vs acc3)
    float* pb = partial + ((size_t)n*NCH + chunk) * SEL;
    for (int e = tid; e < V_*V_; e += 128) {
        const int v = e/V_, u = e%V_;
        float s1=0.f, s2=0.f;
        #pragma unroll
        for (int sl = 0; sl < TTP; ++sl) {
            s1 += A [sl*ATS + v*ROWP + u];
            s2 += A2[sl*ATS + v*ROWP + u];
        }
        pb[e]         = s1;
        pb[V_*V_ + e] = s2;
    }
    __syncthreads();   // A's t-sum flushed; safe to overwrite A with A3

    if (act) {
        float* Ar = &A[slot*ATS];
        #pragma unroll
        for (int a=0;a<5;a++)
            #pragma unroll
            for (int b2=0;b2<5;b2++) {
                Ar[(vt+a)*ROWP + ut+b2] = acc3[a][b2];
                Ar[(ut+b2)*ROWP + vt+a] = acc3[a][b2];
            }
    }
    __syncthreads();

    for (int e = tid; e < V_*V_; e += 128) {
        const int v = e/V_, u = e%V_;
        float s3=0.f;
        #pragma unroll
        for (int sl = 0; sl < TTP; ++sl) s3 += A[sl*ATS + v*ROWP + u];
        pb[2*V_*V_ + e] = s3;
    }
}

// ---------------------------------------------------------------------------
// K1b: Ssum[n][j] = sum over 60 chunks of partial[n][c][j]. Deterministic.
// ---------------------------------------------------------------------------
__global__ __launch_bounds__(256) void k_reduce(const float* __restrict__ partial,
                                                float* __restrict__ Ssum) {
    const int g = blockIdx.x*256 + threadIdx.x;
    if (g >= N_*SEL) return;
    const int n = g / SEL, j = g % SEL;
    const float* p = partial + (size_t)n*NCH*SEL + j;
    float s = 0.f;
    #pragma unroll 4
    for (int c = 0; c < NCH; ++c) s += p[(size_t)c*SEL];
    Ssum[g] = s;
}

// ---------------------------------------------------------------------------
// K2 v4: agg via ONE interleaved u4 loop (6 b128/iter, q's loaded once);
// epilogue reads W/b/gamma/beta from GLOBAL with loop-uniform index ->
// s_load broadcasts through K$, zero LDS-pipe cost (round-4's LDS staging of
// W was the bottleneck: 96 o x 3 ds_read_b128 per wave serialized ~29us/CU).
// ---------------------------------------------------------------------------
__global__ __launch_bounds__(256) void k_out(const float* __restrict__ x,
                                             const float* __restrict__ Ssum,
                                             const float* __restrict__ W,
                                             const float* __restrict__ b,
                                             const float* __restrict__ gamma,
                                             const float* __restrict__ beta,
                                             float* __restrict__ out) {
    const int n = blockIdx.x, tile = blockIdx.y;  // 30 tiles x 10 t
    const int tid = threadIdx.x;

    __shared__ __align__(16) float S_l[3*V_*ROWP];    // 2100
    __shared__ __align__(16) float xsh[TT2*C_*ROWP];  // 840

    const float* xn = x + (size_t)n * C_*T_*V_;
    const int t0 = tile * TT2;

    for (int i = tid; i < 3*V_*ROWP; i += 256) {
        const int s = i/(V_*ROWP), r = i%(V_*ROWP), v = r/ROWP, u = r%ROWP;
        S_l[i] = (u < V_) ? Ssum[(size_t)n*SEL + s*V_*V_ + v*V_ + u] : 0.f;
    }
    for (int i = tid; i < TT2*C_*ROWP; i += 256) {
        const int tt = i/(C_*ROWP), r = i%(C_*ROWP), c = r/ROWP, u = r%ROWP;
        xsh[i] = (u < V_) ? xn[c*(T_*V_) + (t0+tt)*V_ + u] : 0.f;
    }
    __syncthreads();

    if (tid < TT2*V_) {
        const int tt = tid / V_, iv = tid % V_;
        const float* xb = &xsh[tt*C_*ROWP];
        float agg[12];
        agg[0] = (float)T_ * xb[0*ROWP + iv];
        agg[1] = (float)T_ * xb[1*ROWP + iv];
        agg[2] = (float)T_ * xb[2*ROWP + iv];
        #pragma unroll
        for (int k = 3; k < 12; ++k) agg[k] = 0.f;
        const float* S1 = &S_l[0*V_*ROWP + iv*ROWP];
        const float* S2 = &S_l[1*V_*ROWP + iv*ROWP];
        const float* S3 = &S_l[2*V_*ROWP + iv*ROWP];
        #pragma unroll
        for (int u4 = 0; u4 < ROWP; u4 += 4) {
            const float4 q0 = *(const float4*)&xb[0*ROWP + u4];
            const float4 q1 = *(const float4*)&xb[1*ROWP + u4];
            const float4 q2 = *(const float4*)&xb[2*ROWP + u4];
            const float4 s1 = *(const float4*)&S1[u4];
            const float4 s2 = *(const float4*)&S2[u4];
            const float4 s3 = *(const float4*)&S3[u4];
            agg[3]  += s1.x*q0.x + s1.y*q0.y + s1.z*q0.z + s1.w*q0.w;
            agg[4]  += s1.x*q1.x + s1.y*q1.y + s1.z*q1.z + s1.w*q1.w;
            agg[5]  += s1.x*q2.x + s1.y*q2.y + s1.z*q2.z + s1.w*q2.w;
            agg[6]  += s2.x*q0.x + s2.y*q0.y + s2.z*q0.z + s2.w*q0.w;
            agg[7]  += s2.x*q1.x + s2.y*q1.y + s2.z*q1.z + s2.w*q1.w;
            agg[8]  += s2.x*q2.x + s2.y*q2.y + s2.z*q2.z + s2.w*q2.w;
            agg[9]  += s3.x*q0.x + s3.y*q0.y + s3.z*q0.z + s3.w*q0.w;
            agg[10] += s3.x*q1.x + s3.y*q1.y + s3.z*q1.z + s3.w*q1.w;
            agg[11] += s3.x*q2.x + s3.y*q2.y + s3.z*q2.z + s3.w*q2.w;
        }

        const float inv_bn = rsqrtf(1.0f + 1e-5f);
        float* on = out + (size_t)n*(size_t)OUT_*T_*V_ + t0*V_ + tid;
        #pragma unroll 4
        for (int o = 0; o < OUT_; ++o) {
            // W/gamma/b/beta indexed by loop-uniform o -> scalar loads (K$)
            const float4 w0 = *(const float4*)&W[o*12];
            const float4 w1 = *(const float4*)&W[o*12+4];
            const float4 w2 = *(const float4*)&W[o*12+8];
            const float sc = gamma[o] * inv_bn;
            const float of = b[o]*sc + beta[o];
            float acc = w0.x*agg[0] + w0.y*agg[1] + w0.z*agg[2] + w0.w*agg[3]
                      + w1.x*agg[4] + w1.y*agg[5] + w1.z*agg[6] + w1.w*agg[7]
                      + w2.x*agg[8] + w2.y*agg[9] + w2.z*agg[10]+ w2.w*agg[11];
            const float rl = fmaxf(acc*sc + of, 0.f);
            on[(size_t)o*(T_*V_)] = rl;
        }
    }
}

extern "C" void kernel_launch(void* const* d_in, const int* in_sizes, int n_in,
                              void* d_out, int out_size, void* d_ws, size_t ws_size,
                              hipStream_t stream) {
    const float* x     = (const float*)d_in[0];
    const float* xx    = (const float*)d_in[1];
    const float* W     = (const float*)d_in[2];
    const float* b     = (const float*)d_in[3];
    const float* gamma = (const float*)d_in[4];
    const float* beta  = (const float*)d_in[5];
    float* out  = (float*)d_out;

    float* Ssum    = (float*)d_ws;                  // 32*1875 floats = 240 KB
    float* partial = (float*)d_ws + (size_t)N_*SEL; // 1920*1875 floats = 14.4 MB

    k_powsum<<<dim3(N_, NCH), 128, 0, stream>>>(xx, partial);
    k_reduce<<<(N_*SEL + 255)/256, 256, 0, stream>>>(partial, Ssum);
    k_out   <<<dim3(N_, T_/TT2), 256, 0, stream>>>(x, Ssum, W, b, gamma, beta, out);
}

// Round 7
// 92.891 us; speedup vs baseline: 1.0207x; 1.0207x over previous
//
#include <hip/hip_runtime.h>

#define N_   32
#define C_   3
#define T_   300
#define V_   25
#define OUT_ 96
#define ROWP 28              // padded row (float4-aligned)
#define ATS  (V_*ROWP)       // 700 floats per t-slice
#define TTP  5               // t's per k_powsum block
#define NCH  (T_/TTP)        // 60 chunks per n
#define TT2  20              // t's per k_out block (500 floats/o-row, 16B-aligned)
#define NJ   (TT2*V_)        // 500 outputs per o per block
#define AGP  504             // aggT row stride (500 + 4 pad)
#define SEL  (3*V_*V_)       // 1875 floats per sum record

// ---------------------------------------------------------------------------
// K1: block = (n, 5-t chunk), 128 threads, LDS = A + A2 only (29.7 KB).
// Symmetric 5x5-tile matmuls, A3 in registers reusing A's LDS. No atomics.
// (unchanged from round 5/6)
// ---------------------------------------------------------------------------
__global__ __launch_bounds__(128) void k_powsum(const float* __restrict__ xx,
                                                float* __restrict__ partial) {
    const int n = blockIdx.x, chunk = blockIdx.y;
    const int tid = threadIdx.x;

    __shared__ __align__(16) float xs[C_*TTP*ROWP];  // 420
    __shared__ __align__(16) float A [TTP*ATS];      // 3500
    __shared__ __align__(16) float A2[TTP*ATS];      // 3500

    const float* xxn = xx + (size_t)n * C_*T_*V_;
    const int t0 = chunk * TTP;

    for (int i = tid; i < C_*TTP*ROWP; i += 128) {
        const int c = i/(TTP*ROWP), r = i%(TTP*ROWP), t = r/ROWP, u = r%ROWP;
        xs[i] = (u < V_) ? xxn[c*(T_*V_) + (t0+t)*V_ + u] : ((c==0)?1e18f:0.f);
    }
    if (tid < TTP*V_) {
        float* p = &A2[(tid/V_)*ATS + (tid%V_)*ROWP];
        p[25]=0.f; p[26]=0.f; p[27]=0.f;
    }
    __syncthreads();

    if (tid < TTP*V_) {
        const int slot = tid/V_, v = tid%V_;
        const float* x0 = &xs[0*(TTP*ROWP) + slot*ROWP];
        const float* x1 = &xs[1*(TTP*ROWP) + slot*ROWP];
        const float* x2 = &xs[2*(TTP*ROWP) + slot*ROWP];
        const float xv0 = x0[v], xv1 = x1[v], xv2 = x2[v];
        float* Arow = &A[slot*ATS + v*ROWP];
        #pragma unroll
        for (int u4 = 0; u4 < ROWP; u4 += 4) {
            const float4 q0 = *(const float4*)&x0[u4];
            const float4 q1 = *(const float4*)&x1[u4];
            const float4 q2 = *(const float4*)&x2[u4];
            float4 a;
            {   float d0=xv0-q0.x, d1=xv1-q1.x, d2=xv2-q2.x;
                a.x = __expf(-(d0*d0 + d1*d1 + d2*d2)); }
            {   float d0=xv0-q0.y, d1=xv1-q1.y, d2=xv2-q2.y;
                a.y = __expf(-(d0*d0 + d1*d1 + d2*d2)); }
            {   float d0=xv0-q0.z, d1=xv1-q1.z, d2=xv2-q2.z;
                a.z = __expf(-(d0*d0 + d1*d1 + d2*d2)); }
            {   float d0=xv0-q0.w, d1=xv1-q1.w, d2=xv2-q2.w;
                a.w = __expf(-(d0*d0 + d1*d1 + d2*d2)); }
            *(float4*)&Arow[u4] = a;
        }
    }
    __syncthreads();

    const bool act = (tid < TTP*15);
    const int slot = tid / 15;
    int ti = 0, tj = 0;
    {
        int r = tid % 15;
        #pragma unroll
        for (int i = 0; i < 5; ++i) {
            const int cnt = 5 - i;
            if (r < cnt) { ti = i; tj = i + r; break; }
            r -= cnt;
        }
    }
    const int vt = ti*5, ut = tj*5;

    if (act) {
        float acc[5][5];
        #pragma unroll
        for (int a=0;a<5;a++)
            #pragma unroll
            for (int b2=0;b2<5;b2++) acc[a][b2]=0.f;
        const float* Ab = &A[slot*ATS];
        #pragma unroll
        for (int w = 0; w < ROWP; w += 4) {
            float4 ar[5], au[5];
            #pragma unroll
            for (int a=0;a<5;a++) ar[a] = *(const float4*)&Ab[(vt+a)*ROWP + w];
            #pragma unroll
            for (int b2=0;b2<5;b2++) au[b2] = *(const float4*)&Ab[(ut+b2)*ROWP + w];
            #pragma unroll
            for (int a=0;a<5;a++)
                #pragma unroll
                for (int b2=0;b2<5;b2++)
                    acc[a][b2] += ar[a].x*au[b2].x + ar[a].y*au[b2].y
                                + ar[a].z*au[b2].z + ar[a].w*au[b2].w;
        }
        float* A2b = &A2[slot*ATS];
        #pragma unroll
        for (int a=0;a<5;a++)
            #pragma unroll
            for (int b2=0;b2<5;b2++) {
                A2b[(vt+a)*ROWP + ut+b2] = acc[a][b2];
                A2b[(ut+b2)*ROWP + vt+a] = acc[a][b2];
            }
    }
    __syncthreads();

    float acc3[5][5];
    if (act) {
        #pragma unroll
        for (int a=0;a<5;a++)
            #pragma unroll
            for (int b2=0;b2<5;b2++) acc3[a][b2]=0.f;
        const float* Ab  = &A[slot*ATS];
        const float* A2b = &A2[slot*ATS];
        #pragma unroll
        for (int w = 0; w < ROWP; w += 4) {
            float4 ar[5], au[5];
            #pragma unroll
            for (int a=0;a<5;a++) ar[a] = *(const float4*)&A2b[(vt+a)*ROWP + w];
            #pragma unroll
            for (int b2=0;b2<5;b2++) au[b2] = *(const float4*)&Ab[(ut+b2)*ROWP + w];
            #pragma unroll
            for (int a=0;a<5;a++)
                #pragma unroll
                for (int b2=0;b2<5;b2++)
                    acc3[a][b2] += ar[a].x*au[b2].x + ar[a].y*au[b2].y
                                 + ar[a].z*au[b2].z + ar[a].w*au[b2].w;
        }
    }

    float* pb = partial + ((size_t)n*NCH + chunk) * SEL;
    for (int e = tid; e < V_*V_; e += 128) {
        const int v = e/V_, u = e%V_;
        float s1=0.f, s2=0.f;
        #pragma unroll
        for (int sl = 0; sl < TTP; ++sl) {
            s1 += A [sl*ATS + v*ROWP + u];
            s2 += A2[sl*ATS + v*ROWP + u];
        }
        pb[e]         = s1;
        pb[V_*V_ + e] = s2;
    }
    __syncthreads();

    if (act) {
        float* Ar = &A[slot*ATS];
        #pragma unroll
        for (int a=0;a<5;a++)
            #pragma unroll
            for (int b2=0;b2<5;b2++) {
                Ar[(vt+a)*ROWP + ut+b2] = acc3[a][b2];
                Ar[(ut+b2)*ROWP + vt+a] = acc3[a][b2];
            }
    }
    __syncthreads();

    for (int e = tid; e < V_*V_; e += 128) {
        const int v = e/V_, u = e%V_;
        float s3=0.f;
        #pragma unroll
        for (int sl = 0; sl < TTP; ++sl) s3 += A[sl*ATS + v*ROWP + u];
        pb[2*V_*V_ + e] = s3;
    }
}

// ---------------------------------------------------------------------------
// K1b: Ssum[n][j] = sum over 60 chunks. (unchanged)
// ---------------------------------------------------------------------------
__global__ __launch_bounds__(256) void k_reduce(const float* __restrict__ partial,
                                                float* __restrict__ Ssum) {
    const int g = blockIdx.x*256 + threadIdx.x;
    if (g >= N_*SEL) return;
    const int n = g / SEL, j = g % SEL;
    const float* p = partial + (size_t)n*NCH*SEL + j;
    float s = 0.f;
    #pragma unroll 4
    for (int c = 0; c < NCH; ++c) s += p[(size_t)c*SEL];
    Ssum[g] = s;
}

// ---------------------------------------------------------------------------
// K2 v5: block = (n, 20-t tile). Phase A: 500 (t,v) items compute agg[12],
// written TRANSPOSED to LDS aggT[12][504]. Phase B: thread = (o-half, j-quad)
// loads 12 float4 agg regs once, loops 48 o's -> 48 FMA + ONE float4 store
// (coalesced 1KB/wave-inst, 16B-aligned since 500%4==0). W/scale/off from
// LDS same-address broadcast (no s_load chain — that regressed round 6).
// ---------------------------------------------------------------------------
__global__ __launch_bounds__(256) void k_out(const float* __restrict__ x,
                                             const float* __restrict__ Ssum,
                                             const float* __restrict__ W,
                                             const float* __restrict__ b,
                                             const float* __restrict__ gamma,
                                             const float* __restrict__ beta,
                                             float* __restrict__ out) {
    const int n = blockIdx.x, tile = blockIdx.y;  // 15 tiles x 20 t
    const int tid = threadIdx.x;

    __shared__ __align__(16) float S_l[3*V_*ROWP];    // 2100
    __shared__ __align__(16) float xsh[TT2*C_*ROWP];  // 1680
    __shared__ __align__(16) float aggT[12*AGP];      // 6048
    __shared__ __align__(16) float Wl[OUT_*12];       // 1152
    __shared__ float scl[OUT_], off[OUT_];

    const float* xn = x + (size_t)n * C_*T_*V_;
    const int t0 = tile * TT2;
    const float inv_bn = rsqrtf(1.0f + 1e-5f);

    for (int i = tid; i < 3*V_*ROWP; i += 256) {
        const int s = i/(V_*ROWP), r = i%(V_*ROWP), v = r/ROWP, u = r%ROWP;
        S_l[i] = (u < V_) ? Ssum[(size_t)n*SEL + s*V_*V_ + v*V_ + u] : 0.f;
    }
    for (int i = tid; i < TT2*C_*ROWP; i += 256) {
        const int tt = i/(C_*ROWP), r = i%(C_*ROWP), c = r/ROWP, u = r%ROWP;
        xsh[i] = (u < V_) ? xn[c*(T_*V_) + (t0+tt)*V_ + u] : 0.f;
    }
    for (int i = tid; i < OUT_*12; i += 256) Wl[i] = W[i];
    if (tid < OUT_) {
        const float sc = gamma[tid] * inv_bn;
        scl[tid] = sc;
        off[tid] = b[tid]*sc + beta[tid];
    }
    __syncthreads();

    // ---- Phase A: agg for each of 500 (t,v) items, transposed into aggT
    for (int j = tid; j < NJ; j += 256) {
        const int tt = j / V_, iv = j % V_;
        const float* xb = &xsh[tt*C_*ROWP];
        float agg[12];
        agg[0] = (float)T_ * xb[0*ROWP + iv];
        agg[1] = (float)T_ * xb[1*ROWP + iv];
        agg[2] = (float)T_ * xb[2*ROWP + iv];
        #pragma unroll
        for (int k = 3; k < 12; ++k) agg[k] = 0.f;
        const float* S1 = &S_l[0*V_*ROWP + iv*ROWP];
        const float* S2 = &S_l[1*V_*ROWP + iv*ROWP];
        const float* S3 = &S_l[2*V_*ROWP + iv*ROWP];
        #pragma unroll
        for (int u4 = 0; u4 < ROWP; u4 += 4) {
            const float4 q0 = *(const float4*)&xb[0*ROWP + u4];
            const float4 q1 = *(const float4*)&xb[1*ROWP + u4];
            const float4 q2 = *(const float4*)&xb[2*ROWP + u4];
            const float4 s1 = *(const float4*)&S1[u4];
            const float4 s2 = *(const float4*)&S2[u4];
            const float4 s3 = *(const float4*)&S3[u4];
            agg[3]  += s1.x*q0.x + s1.y*q0.y + s1.z*q0.z + s1.w*q0.w;
            agg[4]  += s1.x*q1.x + s1.y*q1.y + s1.z*q1.z + s1.w*q1.w;
            agg[5]  += s1.x*q2.x + s1.y*q2.y + s1.z*q2.z + s1.w*q2.w;
            agg[6]  += s2.x*q0.x + s2.y*q0.y + s2.z*q0.z + s2.w*q0.w;
            agg[7]  += s2.x*q1.x + s2.y*q1.y + s2.z*q1.z + s2.w*q1.w;
            agg[8]  += s2.x*q2.x + s2.y*q2.y + s2.z*q2.z + s2.w*q2.w;
            agg[9]  += s3.x*q0.x + s3.y*q0.y + s3.z*q0.z + s3.w*q0.w;
            agg[10] += s3.x*q1.x + s3.y*q1.y + s3.z*q1.z + s3.w*q1.w;
            agg[11] += s3.x*q2.x + s3.y*q2.y + s3.z*q2.z + s3.w*q2.w;
        }
        #pragma unroll
        for (int k = 0; k < 12; ++k) aggT[k*AGP + j] = agg[k];
    }
    __syncthreads();

    // ---- Phase B: (o-half, j-quad) -> 48 o's x one float4 store each
    const int jq = tid & 127;           // j-quad index, 125 active
    const int oh = tid >> 7;            // o-half: 0 -> o 0..47, 1 -> 48..95
    if (jq < NJ/4) {
        float4 a[12];
        #pragma unroll
        for (int k = 0; k < 12; ++k) a[k] = *(const float4*)&aggT[k*AGP + 4*jq];

        float* on = out + (size_t)n*(size_t)OUT_*T_*V_ + tile*NJ + 4*jq;
        const int o0 = oh * (OUT_/2);
        #pragma unroll 2
        for (int o = o0; o < o0 + OUT_/2; ++o) {
            const float4 w0 = *(const float4*)&Wl[o*12];
            const float4 w1 = *(const float4*)&Wl[o*12+4];
            const float4 w2 = *(const float4*)&Wl[o*12+8];
            const float sc = scl[o], of = off[o];
            float4 r;
            r.x = w0.x*a[0].x + w0.y*a[1].x + w0.z*a[2].x + w0.w*a[3].x
                + w1.x*a[4].x + w1.y*a[5].x + w1.z*a[6].x + w1.w*a[7].x
                + w2.x*a[8].x + w2.y*a[9].x + w2.z*a[10].x+ w2.w*a[11].x;
            r.y = w0.x*a[0].y + w0.y*a[1].y + w0.z*a[2].y + w0.w*a[3].y
                + w1.x*a[4].y + w1.y*a[5].y + w1.z*a[6].y + w1.w*a[7].y
                + w2.x*a[8].y + w2.y*a[9].y + w2.z*a[10].y+ w2.w*a[11].y;
            r.z = w0.x*a[0].z + w0.y*a[1].z + w0.z*a[2].z + w0.w*a[3].z
                + w1.x*a[4].z + w1.y*a[5].z + w1.z*a[6].z + w1.w*a[7].z
                + w2.x*a[8].z + w2.y*a[9].z + w2.z*a[10].z+ w2.w*a[11].z;
            r.w = w0.x*a[0].w + w0.y*a[1].w + w0.z*a[2].w + w0.w*a[3].w
                + w1.x*a[4].w + w1.y*a[5].w + w1.z*a[6].w + w1.w*a[7].w
                + w2.x*a[8].w + w2.y*a[9].w + w2.z*a[10].w+ w2.w*a[11].w;
            r.x = fmaxf(r.x*sc + of, 0.f);
            r.y = fmaxf(r.y*sc + of, 0.f);
            r.z = fmaxf(r.z*sc + of, 0.f);
            r.w = fmaxf(r.w*sc + of, 0.f);
            *(float4*)&on[(size_t)o*(T_*V_)] = r;
        }
    }
}

extern "C" void kernel_launch(void* const* d_in, const int* in_sizes, int n_in,
                              void* d_out, int out_size, void* d_ws, size_t ws_size,
                              hipStream_t stream) {
    const float* x     = (const float*)d_in[0];
    const float* xx    = (const float*)d_in[1];
    const float* W     = (const float*)d_in[2];
    const float* b     = (const float*)d_in[3];
    const float* gamma = (const float*)d_in[4];
    const float* beta  = (const float*)d_in[5];
    float* out  = (float*)d_out;

    float* Ssum    = (float*)d_ws;                  // 240 KB
    float* partial = (float*)d_ws + (size_t)N_*SEL; // 14.4 MB

    k_powsum<<<dim3(N_, NCH), 128, 0, stream>>>(xx, partial);
    k_reduce<<<(N_*SEL + 255)/256, 256, 0, stream>>>(partial, Ssum);
    k_out   <<<dim3(N_, T_/TT2), 256, 0, stream>>>(x, Ssum, W, b, gamma, beta, out);
}